// Round 7
// baseline (20005.774 us; speedup 1.0000x reference)
//
#include <hip/hip_runtime.h>
#include <cstddef>

// Problem constants
#define LL 512
#define BB 64
#define EE 512
#define HH 512
#define TT 16
#define START_TAG 14
#define STOP_TAG 15
#define NBLK_DIR 128u   // lstm blocks per direction

typedef unsigned short u16;
typedef unsigned int u32;

__device__ __forceinline__ u16 f2bf(float f) {
  u32 u = __builtin_bit_cast(u32, f);
  u32 r = u + 0x7FFFu + ((u >> 16) & 1u);
  return (u16)(r >> 16);
}
__device__ __forceinline__ float bf2f(u16 h) {
  return __builtin_bit_cast(float, (u32)h << 16);
}

// ---------------------------------------------------------------------------
// K1: XPT[t][col][g][b] = embed[tok(t,b)] . Wih_dir[g*512+col] + b_dir[...]
// bf16 output. 128x128 tile, BK=16, 256 threads, 8x8/thread f32 VALU GEMM.
// ---------------------------------------------------------------------------
#define AP 132  // padded LDS leading dim

__global__ __launch_bounds__(256) void gemm_xp(
    const int* __restrict__ sent, const float* __restrict__ embed,
    const float* __restrict__ Wf, const float* __restrict__ Wb,
    const float* __restrict__ bf, const float* __restrict__ bb,
    u16* __restrict__ XPf, u16* __restrict__ XPb)
{
  __shared__ float Al[16 * AP];
  __shared__ float Bl[16 * AP];
  __shared__ int tok[128];

  const int bid = blockIdx.x;
  const int mt = bid & 255;       // 256 m-tiles
  const int nt = bid >> 8;        // 32 n-tiles
  const int m0 = mt << 7;
  const int n0g = nt << 7;
  const int dir = n0g >> 11;      // 0 fwd / 1 bwd
  const int n0 = n0g & 2047;
  const float* W = dir ? Wb : Wf;
  const float* bias = dir ? bb : bf;
  u16* XP = dir ? XPb : XPf;
  const int tid = threadIdx.x;

  if (tid < 128) {
    int m = m0 + tid;
    int l = m >> 6, b = m & 63;
    tok[tid] = sent[b * LL + l];
  }
  __syncthreads();

  float acc[8][8];
#pragma unroll
  for (int i = 0; i < 8; ++i)
#pragma unroll
    for (int j = 0; j < 8; ++j) acc[i][j] = 0.f;

  const int ty = tid >> 4, tx = tid & 15;

#pragma unroll 1
  for (int k0 = 0; k0 < EE; k0 += 16) {
    __syncthreads();
    for (int i = tid; i < 512; i += 256) {
      int row = i >> 2, q = i & 3;
      float4 va = *(const float4*)(embed + (size_t)tok[row] * EE + k0 + q * 4);
      Al[(q * 4 + 0) * AP + row] = va.x;
      Al[(q * 4 + 1) * AP + row] = va.y;
      Al[(q * 4 + 2) * AP + row] = va.z;
      Al[(q * 4 + 3) * AP + row] = va.w;
      float4 vb = *(const float4*)(W + (size_t)(n0 + row) * EE + k0 + q * 4);
      Bl[(q * 4 + 0) * AP + row] = vb.x;
      Bl[(q * 4 + 1) * AP + row] = vb.y;
      Bl[(q * 4 + 2) * AP + row] = vb.z;
      Bl[(q * 4 + 3) * AP + row] = vb.w;
    }
    __syncthreads();
#pragma unroll
    for (int kk = 0; kk < 16; ++kk) {
      float4 a0 = *(const float4*)(Al + kk * AP + ty * 8);
      float4 a1 = *(const float4*)(Al + kk * AP + ty * 8 + 4);
      float4 b0 = *(const float4*)(Bl + kk * AP + tx * 8);
      float4 b1 = *(const float4*)(Bl + kk * AP + tx * 8 + 4);
      float av[8] = {a0.x, a0.y, a0.z, a0.w, a1.x, a1.y, a1.z, a1.w};
      float bv[8] = {b0.x, b0.y, b0.z, b0.w, b1.x, b1.y, b1.z, b1.w};
#pragma unroll
      for (int i = 0; i < 8; ++i)
#pragma unroll
        for (int j = 0; j < 8; ++j) acc[i][j] = fmaf(av[i], bv[j], acc[i][j]);
    }
  }

  float bval[8];
#pragma unroll
  for (int j = 0; j < 8; ++j) bval[j] = bias[n0 + tx * 8 + j];

#pragma unroll
  for (int i = 0; i < 8; ++i) {
    const int m = m0 + ty * 8 + i;
    const int t = m >> 6, b = m & 63;
#pragma unroll
    for (int j = 0; j < 8; ++j) {
      const int n = n0 + tx * 8 + j;      // 0..2047 within direction
      const int col = n & 511, g = n >> 9;
      XP[(((size_t)t * HH + col) * 4 + g) * BB + b] = f2bf(acc[i][j] + bval[j]);
    }
  }
}

// ---------------------------------------------------------------------------
// Lightweight per-direction grid barrier (monotonic phase, thread-0 spin).
// ---------------------------------------------------------------------------
__device__ __forceinline__ void dir_barrier(unsigned* cnt, unsigned* rel,
                                            unsigned phase) {
  __syncthreads();   // all waves drained (vmcnt(0) before s_barrier)
  if (threadIdx.x == 0) {
    __threadfence();  // release
    unsigned old = __hip_atomic_fetch_add(cnt, 1u, __ATOMIC_RELAXED,
                                          __HIP_MEMORY_SCOPE_AGENT);
    if (old == phase * NBLK_DIR - 1u) {
      __hip_atomic_store(rel, phase, __ATOMIC_RELEASE, __HIP_MEMORY_SCOPE_AGENT);
    } else {
      while (__hip_atomic_load(rel, __ATOMIC_ACQUIRE, __HIP_MEMORY_SCOPE_AGENT) < phase)
        __builtin_amdgcn_s_sleep(1);
    }
    __threadfence();  // acquire
  }
  __syncthreads();
}

// ---------------------------------------------------------------------------
// K2: BiLSTM recurrence. 256 blocks x 512 threads (128 blocks/dir).
// Block owns 4 hidden cols. Wave wv: col = c0 + (wv&3), khalf = wv>>2.
// lane = batch b. h is bf16, staged to LDS once per block per step
// ([k-pair][b][2] interleave, exactly 64 KB). Weights s-loaded (uniform).
// Partial sums for khalf=1 pass through 4 KB LDS scratch aliased over h.
// ---------------------------------------------------------------------------
__global__ __launch_bounds__(512) void lstm_rec(
    const u16* __restrict__ XPTf, const u16* __restrict__ XPTb,
    const float* __restrict__ Whh_f, const float* __restrict__ Whh_b,
    const float* __restrict__ h0, const float* __restrict__ c0,
    u16* __restrict__ hbuf,        // [2 dir][2 buf][32768] bf16 pair-layout
    float* __restrict__ hs,        // [512*64][1024] f32
    unsigned* __restrict__ bar)    // cnt_f@0, cnt_b@32, rel_f@64, rel_b@96
{
  extern __shared__ u32 ldsH[];    // 16384 dwords = 64 KB (h staging + scratch alias)
  float4* part = (float4*)ldsH;    // alias: valid only after k-loop sync

  const int bid = blockIdx.x;
  const int dir = bid >> 7;
  const int cblk = bid & 127;
  const int c0col = cblk << 2;
  const int tid = threadIdx.x;
  const int wv = __builtin_amdgcn_readfirstlane(tid >> 6);
  const int lane = tid & 63;             // batch b
  const int mycol = c0col + (wv & 3);    // this wave's hidden column
  const int khalf = wv >> 2;             // 0: k 0..255, 1: k 256..511

  const float* Whh = dir ? Whh_b : Whh_f;
  const u16* XP = dir ? XPTb : XPTf;
  u16* hA = hbuf + (size_t)dir * 2 * HH * BB;
  u16* hB = hA + HH * BB;
  unsigned* cnt = bar + (dir ? 32 : 0);
  unsigned* rel = bar + (dir ? 96 : 64);

  // wave-uniform weight row pointers (float4 view), offset by khalf
  const float4* W0 = (const float4*)(Whh + ((size_t)0 * HH + mycol) * HH + khalf * 256);
  const float4* W1 = (const float4*)(Whh + ((size_t)1 * HH + mycol) * HH + khalf * 256);
  const float4* W2 = (const float4*)(Whh + ((size_t)2 * HH + mycol) * HH + khalf * 256);
  const float4* W3 = (const float4*)(Whh + ((size_t)3 * HH + mycol) * HH + khalf * 256);

  // init: update threads (tid<256) own (col = c0col + (tid>>6), b = tid&63)
  float creg = 0.f;
  if (tid < 256) {
    const int ucol = c0col + (tid >> 6), b = tid & 63;
    creg = c0[(size_t)dir * BB * HH + (size_t)b * HH + ucol];
    const float hv0 = h0[(size_t)dir * BB * HH + (size_t)b * HH + ucol];
    hA[(ucol >> 1) * 128 + b * 2 + (ucol & 1)] = f2bf(hv0);
  }

  unsigned phase = 1;
  dir_barrier(cnt, rel, phase++);

#pragma unroll 1
  for (int step = 0; step < LL; ++step) {
    const int t = dir ? (LL - 1 - step) : step;
    const u16* hcur = (step & 1) ? hB : hA;
    u16* hnxt = (step & 1) ? hA : hB;

    // ---- stage h (64 KB bf16) global -> LDS, 8 x uint4 per thread ----
    {
      const uint4* src = (const uint4*)hcur;
#pragma unroll
      for (int i = 0; i < 8; ++i) {
        ((uint4*)ldsH)[i * 512 + tid] = src[i * 512 + tid];
      }
    }
    __syncthreads();

    // ---- XP prefetch for update threads (latency hides under k-loop) ----
    float xp0 = 0.f, xp1 = 0.f, xp2 = 0.f, xp3 = 0.f;
    if (tid < 256) {
      const int ucol = c0col + (tid >> 6), b = tid & 63;
      const u16* xpp = XP + ((size_t)t * HH + ucol) * 4 * BB + b;
      xp0 = bf2f(xpp[0]);
      xp1 = bf2f(xpp[BB]);
      xp2 = bf2f(xpp[2 * BB]);
      xp3 = bf2f(xpp[3 * BB]);
    }

    // ---- k-loop: 256 k per wave, h pairs from LDS, weights s-loaded ----
    float a0 = 0.f, a1 = 0.f, a2 = 0.f, a3 = 0.f;
    const u32* hp = ldsH + khalf * 8192;   // 128 pairs * 64 b dwords
#pragma unroll 8
    for (int p = 0; p < 128; p += 2) {
      const u32 v0 = hp[p * 64 + lane];
      const u32 v1 = hp[(p + 1) * 64 + lane];
      const float4 w0 = W0[p >> 1];
      const float4 w1 = W1[p >> 1];
      const float4 w2 = W2[p >> 1];
      const float4 w3 = W3[p >> 1];
      const float h0f = __builtin_bit_cast(float, v0 << 16);
      const float h1f = __builtin_bit_cast(float, v0 & 0xFFFF0000u);
      const float h2f = __builtin_bit_cast(float, v1 << 16);
      const float h3f = __builtin_bit_cast(float, v1 & 0xFFFF0000u);
      a0 = fmaf(h0f, w0.x, a0); a1 = fmaf(h0f, w1.x, a1);
      a2 = fmaf(h0f, w2.x, a2); a3 = fmaf(h0f, w3.x, a3);
      a0 = fmaf(h1f, w0.y, a0); a1 = fmaf(h1f, w1.y, a1);
      a2 = fmaf(h1f, w2.y, a2); a3 = fmaf(h1f, w3.y, a3);
      a0 = fmaf(h2f, w0.z, a0); a1 = fmaf(h2f, w1.z, a1);
      a2 = fmaf(h2f, w2.z, a2); a3 = fmaf(h2f, w3.z, a3);
      a0 = fmaf(h3f, w0.w, a0); a1 = fmaf(h3f, w1.w, a1);
      a2 = fmaf(h3f, w2.w, a2); a3 = fmaf(h3f, w3.w, a3);
    }

    __syncthreads();                 // h staging dead from here; part alias ok
    if (wv >= 4) {                   // khalf=1 waves export partials
      part[(wv - 4) * 64 + lane] = make_float4(a0, a1, a2, a3);
    }
    __syncthreads();

    if (tid < 256) {                 // khalf=0 waves do the cell update
      const int ucol = c0col + (tid >> 6), b = tid & 63;
      const float4 o = part[wv * 64 + lane];   // partner wave wv+4 partial
      const float g0 = a0 + o.x + xp0;
      const float g1 = a1 + o.y + xp1;
      const float g2 = a2 + o.z + xp2;
      const float g3 = a3 + o.w + xp3;
      const float ig = 1.f / (1.f + expf(-g0));
      const float fg = 1.f / (1.f + expf(-g1));
      const float gg = tanhf(g2);
      const float og = 1.f / (1.f + expf(-g3));
      creg = fg * creg + ig * gg;
      const float hv = og * tanhf(creg);
      hnxt[(ucol >> 1) * 128 + b * 2 + (ucol & 1)] = f2bf(hv);
      hs[((size_t)t * BB + b) * 1024 + dir * HH + ucol] = hv;
    }

    dir_barrier(cnt, rel, phase++);
  }
}

// ---------------------------------------------------------------------------
// K3a: feats[b][l][tag] = hs[l*64+b][:] . W_tag[tag][:] + b_tag[tag]
// ---------------------------------------------------------------------------
__global__ __launch_bounds__(64) void feats_k(
    const float* __restrict__ hs, const float* __restrict__ Wt,
    const float* __restrict__ bt, float* __restrict__ feats)
{
  const int bid = blockIdx.x;
  const int l = bid >> 6, b = bid & 63;
  const int tid = threadIdx.x;
  const int tag = tid & 15, q = tid >> 4;
  const float* hrow = hs + ((size_t)l * BB + b) * 1024;
  const float* wrow = Wt + tag * 1024;
  float p = 0.f;
#pragma unroll 4
  for (int i = 0; i < 64; ++i) {
    int k = q * 256 + i * 4;
    float4 h4 = *(const float4*)(hrow + k);
    float4 w4 = *(const float4*)(wrow + k);
    p += h4.x * w4.x + h4.y * w4.y + h4.z * w4.z + h4.w * w4.w;
  }
  p += __shfl_xor(p, 16);
  p += __shfl_xor(p, 32);
  if (q == 0) feats[((size_t)b * LL + l) * TT + tag] = p + bt[tag];
}

// ---------------------------------------------------------------------------
// K3b: Viterbi per sentence. Strict '>' preserves jnp.argmax tie-break.
// ---------------------------------------------------------------------------
__global__ __launch_bounds__(64) void viterbi_k(
    const float* __restrict__ feats, const float* __restrict__ trans,
    float* __restrict__ out)
{
  __shared__ float fv[TT];
  __shared__ unsigned char bps[LL * TT];
  const int b = blockIdx.x;
  const int tid = threadIdx.x;

  float trow[16];
  if (tid < 16) {
#pragma unroll
    for (int p = 0; p < 16; ++p) trow[p] = trans[tid * TT + p];
    fv[tid] = (tid == START_TAG) ? 0.f : -10000.f;
  }
  __syncthreads();

  const float* fb = feats + (size_t)b * LL * TT;
#pragma unroll 1
  for (int t = 0; t < LL; ++t) {
    float best = 0.f; int barg = 0;
    if (tid < 16) {
      best = fv[0] + trow[0]; barg = 0;
#pragma unroll
      for (int p = 1; p < 16; ++p) {
        float s = fv[p] + trow[p];
        if (s > best) { best = s; barg = p; }
      }
      bps[t * TT + tid] = (unsigned char)barg;
    }
    __syncthreads();
    if (tid < 16) fv[tid] = best + fb[t * TT + tid];
    __syncthreads();
  }

  if (tid == 0) {
    float bsc = fv[0] + trans[STOP_TAG * TT + 0];
    int btag = 0;
#pragma unroll
    for (int j = 1; j < 16; ++j) {
      float s = fv[j] + trans[STOP_TAG * TT + j];
      if (s > bsc) { bsc = s; btag = j; }
    }
    out[b] = bsc;
    int tg = btag;
    for (int t = LL - 1; t >= 0; --t) {
      out[BB + b * LL + t] = (float)tg;
      tg = bps[t * TT + tg];
    }
  }
}

// ---------------------------------------------------------------------------
extern "C" void kernel_launch(void* const* d_in, const int* in_sizes, int n_in,
                              void* d_out, int out_size, void* d_ws, size_t ws_size,
                              hipStream_t stream)
{
  (void)in_sizes; (void)n_in; (void)out_size;
  const int* sent = (const int*)d_in[0];
  const float* embed = (const float*)d_in[1];
  const float* Wih_f = (const float*)d_in[2];
  const float* Whh_f = (const float*)d_in[3];
  const float* b_f = (const float*)d_in[4];
  const float* Wih_b = (const float*)d_in[5];
  const float* Whh_b = (const float*)d_in[6];
  const float* b_b = (const float*)d_in[7];
  const float* h0 = (const float*)d_in[8];
  const float* c0 = (const float*)d_in[9];
  const float* Wt = (const float*)d_in[10];
  const float* bt = (const float*)d_in[11];
  const float* trans = (const float*)d_in[12];
  float* out = (float*)d_out;

  const size_t XPE = (size_t)LL * HH * 4 * BB;           // 67,108,864 per dir
  const size_t XP_B = XPE * 2;                           // bf16 bytes per dir
  const size_t HBUF_B = 2ull * 2 * HH * BB * 2;          // 256 KiB bf16
  const size_t HS_B = (size_t)LL * BB * 1024 * 4;        // 128 MiB
  const size_t FEATS_B = (size_t)BB * LL * TT * 4;       // 2 MiB
  const size_t need = 1024 + 2 * XP_B + HBUF_B + HS_B + FEATS_B;  // ~386.3 MiB

  if (ws_size < need) return;   // clean diagnostic failure, no device fault

  char* wsb = (char*)d_ws;
  unsigned* bar = (unsigned*)wsb;
  u16* XPTf = (u16*)(wsb + 1024);
  u16* XPTb = (u16*)(wsb + 1024 + XP_B);
  u16* hbuf = (u16*)(wsb + 1024 + 2 * XP_B);
  float* hs = (float*)(wsb + 1024 + 2 * XP_B + HBUF_B);
  float* feats = (float*)(wsb + 1024 + 2 * XP_B + HBUF_B + HS_B);

  hipMemsetAsync(wsb, 0, 1024, stream);   // barrier counters

  hipLaunchKernelGGL(gemm_xp, dim3(8192), dim3(256), 0, stream,
                     sent, embed, Wih_f, Wih_b, b_f, b_b, XPTf, XPTb);

  void* ka[9];
  ka[0] = (void*)&XPTf; ka[1] = (void*)&XPTb;
  ka[2] = (void*)&Whh_f; ka[3] = (void*)&Whh_b;
  ka[4] = (void*)&h0;  ka[5] = (void*)&c0;
  ka[6] = (void*)&hbuf; ka[7] = (void*)&hs; ka[8] = (void*)&bar;
  hipLaunchCooperativeKernel((void*)lstm_rec, dim3(256), dim3(512),
                             ka, 65536, stream);

  hipLaunchKernelGGL(feats_k, dim3(32768), dim3(64), 0, stream, hs, Wt, bt, feats);
  hipLaunchKernelGGL(viterbi_k, dim3(64), dim3(64), 0, stream, feats, trans, out);
}